// Round 6
// baseline (1762.094 us; speedup 1.0000x reference)
//
#include <hip/hip_runtime.h>
#include <math.h>

#define BB 8
#define TT 128
#define NN 512
#define DD 2048      // N*HID
#define EE 16384
#define KTOT 4096    // 2048 (x) + 2048 (h)
#define NKB 128      // KTOT/32 kblocks
#define FPAD 16      // flag padding (dwords) -> one flag per 64 B

typedef __attribute__((ext_vector_type(8))) short short8;
typedef __attribute__((ext_vector_type(4))) float f32x4;

__device__ __forceinline__ float b2f(unsigned short u) {
    union { unsigned int i; float f; } v; v.i = ((unsigned int)u) << 16; return v.f;
}
__device__ __forceinline__ unsigned short f2b(float f) {
    union { float f; unsigned int i; } v; v.f = f;
    unsigned int r = v.i + 0x7fff + ((v.i >> 16) & 1);
    return (unsigned short)(r >> 16);
}

// ---------------- fused GAT: one kernel, no CSR, no max pass ----------------
// Block t (128 blocks x 512 thr): LDS softmax sums via ds f32 atomics over the
// 16384 edges (all touch batch-0 nodes), then write all 8 batches' outputs.
// exp without max-subtraction: ratios identical; |e| <~ 25 so f32 is safe.
__global__ __launch_bounds__(512) void k_gat(const float* __restrict__ xseq,
                                             const float* __restrict__ W,
                                             const float* __restrict__ as,
                                             const float* __restrict__ ad,
                                             const float* __restrict__ bias,
                                             const int* __restrict__ ei,
                                             unsigned short* __restrict__ seqout) {
    __shared__ float xr[NN], num[NN], den[NN];
    const int t = blockIdx.x;
    const int j = threadIdx.x;
    xr[j] = xseq[t * NN + j];          // batch 0 slice
    num[j] = 0.f;
    den[j] = 0.f;

    const float w0 = W[0], w1 = W[1], w2 = W[2], w3 = W[3];
    const float cs = w0 * as[0] + w1 * as[1] + w2 * as[2] + w3 * as[3];
    const float cd = w0 * ad[0] + w1 * ad[1] + w2 * ad[2] + w3 * ad[3];
    __syncthreads();

    for (int e = j; e < EE; e += NN) {
        const int s = ei[e], d = ei[EE + e];
        float v = cs * xr[s] + cd * xr[d];
        v = v > 0.f ? v : 0.2f * v;
        const float wt = expf(v);
        atomicAdd(&den[d], wt);
        atomicAdd(&num[d], wt * xr[s]);
    }
    __syncthreads();

    const float b0 = bias[0], b1 = bias[1], b2 = bias[2], b3 = bias[3];

    // batch 0: attention + self-loop
    {
        const float xj = xr[j];
        float e0 = (cs + cd) * xj;
        e0 = e0 > 0.f ? e0 : 0.2f * e0;
        const float we = expf(e0);
        const float y = (num[j] + we * xj) / (den[j] + we);
        ushort4 o;
        o.x = f2b(fmaxf(w0 * y + b0, 0.f));
        o.y = f2b(fmaxf(w1 * y + b1, 0.f));
        o.z = f2b(fmaxf(w2 * y + b2, 0.f));
        o.w = f2b(fmaxf(w3 * y + b3, 0.f));
        *(ushort4*)(seqout + (size_t)t * BB * DD + (size_t)j * 4) = o;
    }
    // batches 1..7: self-loop only
#pragma unroll
    for (int b = 1; b < 8; ++b) {
        const float x = xseq[((size_t)b * TT + t) * NN + j];
        ushort4 o;
        o.x = f2b(fmaxf(w0 * x + b0, 0.f));
        o.y = f2b(fmaxf(w1 * x + b1, 0.f));
        o.z = f2b(fmaxf(w2 * x + b2, 0.f));
        o.w = f2b(fmaxf(w3 * x + b3, 0.f));
        *(ushort4*)(seqout + (size_t)t * BB * DD + (size_t)b * DD + (size_t)j * 4) = o;
    }
}

// ---------------- weight pack: f32 -> bf16 B-fragment tiles ----------------
__global__ __launch_bounds__(256) void k_pack_w(const float* __restrict__ wih,
                                                const float* __restrict__ whh,
                                                unsigned short* __restrict__ WP) {
    const int pair = blockIdx.x * 4 + (threadIdx.x >> 6);  // (s,kb): 0..65535
    const int lane = threadIdx.x & 63;
    const int s = pair >> 7, kb = pair & 127;
    const int n = lane >> 2, quad = lane & 3;
    const int d = (s >> 1) * 8 + (s & 1) * 4 + (n & 3);
    const int row = (n >> 2) * 2048 + d;
    const int k = kb * 32 + quad * 8;
    const float* src = (k < 2048) ? (wih + (size_t)row * 2048 + k)
                                  : (whh + (size_t)row * 2048 + (k - 2048));
    const float4 f0 = ((const float4*)src)[0];
    const float4 f1 = ((const float4*)src)[1];
    unsigned int u0 = (unsigned int)f2b(f0.x) | ((unsigned int)f2b(f0.y) << 16);
    unsigned int u1 = (unsigned int)f2b(f0.z) | ((unsigned int)f2b(f0.w) << 16);
    unsigned int u2 = (unsigned int)f2b(f1.x) | ((unsigned int)f2b(f1.y) << 16);
    unsigned int u3 = (unsigned int)f2b(f1.z) | ((unsigned int)f2b(f1.w) << 16);
    ((uint4*)WP)[(size_t)pair * 64 + quad * 16 + n] = make_uint4(u0, u1, u2, u3);
}

// ---------------- zero h buffers + barrier flags ----------------

__global__ void k_zero(unsigned int* __restrict__ hb, unsigned int* __restrict__ bar) {
    int i = blockIdx.x * blockDim.x + threadIdx.x;
    if (i < 16384) hb[i] = 0u;     // hb0 + hb1 (64 KB)
    if (i < 256 * FPAD) bar[i] = 0u;
}

// ---------------- persistent LSTM ----------------
// 256 blocks x 1024 thr (cooperative). Block b: d0=8b..8b+7 = strips 2b, 2b+1.
// Wave (st=w>>3, ke=w&7): x-kblocks [ke*8,+8) and h-kblocks [64+ke*8,+8); its 16
// weight B-frags live in registers (loaded once). Per step: 8 x-MFMAs run BEFORE
// the flag poll (A-frags straight from L2-resident seq); post-barrier only the
// h-path: 16 sc1 8B loads (direct from L3, no LDS) + 8 MFMAs + reduce + gates.
__global__ __launch_bounds__(1024, 4) void k_lstm_persist(
    const unsigned short* __restrict__ seq, const uint4* __restrict__ WPq,
    const float* __restrict__ b_ih, const float* __restrict__ b_hh,
    unsigned short* __restrict__ hb0, unsigned short* __restrict__ hb1,
    unsigned int* __restrict__ flags) {
    __shared__ float red[2][8][32][4];      // 8 KB k-partial D
    __shared__ float zbuf[4][8][8];         // [gate][d_local][batch]
    __shared__ float biasL[32];

    const int tid = threadIdx.x;
    const int wave = tid >> 6, lane = tid & 63;
    const int st = wave >> 3, ke = wave & 7;
    const int d0 = blockIdx.x * 8;
    const size_t sglob = (size_t)blockIdx.x * 2 + st;

    if (tid < 32) {
        const int g = tid >> 3, dl = tid & 7;
        const int row = g * 2048 + d0 + dl;
        biasL[tid] = b_ih[row] + b_hh[row];
    }

    // load this wave's 16 weight fragments into registers (once):
    // w[0..7] = x-kblocks ke*8+i, w[8..15] = h-kblocks 64+ke*8+i
    uint4 w[16];
    {
        const uint4* wpx = WPq + (sglob * NKB + (size_t)ke * 8) * 64 + lane;
        const uint4* wph = WPq + (sglob * NKB + 64 + (size_t)ke * 8) * 64 + lane;
#pragma unroll
        for (int i = 0; i < 8; ++i) {
            w[i] = wpx[i * 64];
            w[8 + i] = wph[i * 64];
        }
    }

    const int batch = lane & 7;            // m rows 8-15 duplicate 0-7 (ignored)
    const int quad = lane >> 4;
    const int xoff = batch * DD + ke * 256 + quad * 8;            // shorts
    const int hqoff = batch * 512 + ke * 64 + quad * 2;           // 8B units

    float creg0 = 0.f, creg1 = 0.f;   // c for tid<32: (batch=tid>>2, d=d0+(tid&3)*2 {+1})

    for (int t = 0; t < TT; ++t) {
        const unsigned short* xt = seq + (size_t)t * BB * DD;
        const unsigned short* hin = (t & 1) ? hb1 : hb0;
        unsigned short* hout = (t & 1) ? hb0 : hb1;

        // ---- x phase: no dependence on barrier; overlaps other blocks' tails
        f32x4 c0 = {0.f, 0.f, 0.f, 0.f}, c1 = {0.f, 0.f, 0.f, 0.f};
        {
            uint4 ax[8];
#pragma unroll
            for (int i = 0; i < 8; ++i)
                ax[i] = *(const uint4*)(xt + xoff + i * 32);
#pragma unroll
            for (int i = 0; i < 8; ++i) {
                short8 a, b;
                __builtin_memcpy(&a, &ax[i], 16);
                __builtin_memcpy(&b, &w[i], 16);
                if (i & 1) c1 = __builtin_amdgcn_mfma_f32_16x16x32_bf16(a, b, c1, 0, 0, 0);
                else       c0 = __builtin_amdgcn_mfma_f32_16x16x32_bf16(a, b, c0, 0, 0, 0);
            }
        }

        // ---- barrier: wait for all 256 flag stores of step t-1
        if (t > 0 && tid < 256) {
            const unsigned int gen = (unsigned int)t;
            while (__hip_atomic_load(&flags[tid * FPAD], __ATOMIC_RELAXED,
                                     __HIP_MEMORY_SCOPE_AGENT) < gen) {}
        }
        __syncthreads();

        // ---- h phase: A-frags via sc1 8B loads straight from L3
        {
            const unsigned long long* hq = (const unsigned long long*)hin;
            unsigned long long ah[8][2];
#pragma unroll
            for (int i = 0; i < 8; ++i) {
                ah[i][0] = __hip_atomic_load(&hq[hqoff + i * 8], __ATOMIC_RELAXED,
                                             __HIP_MEMORY_SCOPE_AGENT);
                ah[i][1] = __hip_atomic_load(&hq[hqoff + i * 8 + 1], __ATOMIC_RELAXED,
                                             __HIP_MEMORY_SCOPE_AGENT);
            }
#pragma unroll
            for (int i = 0; i < 8; ++i) {
                short8 a, b;
                __builtin_memcpy(&a, &ah[i][0], 16);
                __builtin_memcpy(&b, &w[8 + i], 16);
                if (i & 1) c1 = __builtin_amdgcn_mfma_f32_16x16x32_bf16(a, b, c1, 0, 0, 0);
                else       c0 = __builtin_amdgcn_mfma_f32_16x16x32_bf16(a, b, c0, 0, 0, 0);
            }
        }
        f32x4 acc = c0 + c1;
        if (lane < 32) *(f32x4*)&red[st][ke][lane][0] = acc;
        __syncthreads();

        // reduce 8 k-partials -> zbuf (C layout: col=lane&15, row=(lane>>4)*4+reg)
        if (tid < 256) {
            const int st2 = tid >> 7, l2 = (tid & 127) >> 2, reg = tid & 3;
            float z = 0.f;
#pragma unroll
            for (int kk = 0; kk < 8; ++kk) z += red[st2][kk][l2][reg];
            const int bb = (l2 >> 4) * 4 + reg;
            const int n = l2 & 15;
            zbuf[n >> 2][st2 * 4 + (n & 3)][bb] = z;
        }
        __syncthreads();

        if (tid < 32) {
            const int bb = tid >> 2, dp = (tid & 3) << 1;
            float h2[2];
#pragma unroll
            for (int q = 0; q < 2; ++q) {
                const int dl = dp + q;
                const float zi = zbuf[0][dl][bb] + biasL[dl];
                const float zf = zbuf[1][dl][bb] + biasL[8 + dl];
                const float zg = zbuf[2][dl][bb] + biasL[16 + dl];
                const float zo = zbuf[3][dl][bb] + biasL[24 + dl];
                const float si = 1.f / (1.f + expf(-zi));
                const float sf = 1.f / (1.f + expf(-zf));
                const float so = 1.f / (1.f + expf(-zo));
                const float tg = tanhf(zg);
                float& cr = q ? creg1 : creg0;
                cr = sf * cr + si * tg;
                h2[q] = so * tanhf(cr);
            }
            const unsigned int pk = (unsigned int)f2b(h2[0]) |
                                    ((unsigned int)f2b(h2[1]) << 16);
            unsigned int* hp = (unsigned int*)(hout + bb * DD + d0) + (tid & 3);
            __hip_atomic_store(hp, pk, __ATOMIC_RELAXED, __HIP_MEMORY_SCOPE_AGENT);
        }
        if (t != TT - 1) {
            __builtin_amdgcn_s_waitcnt(0);   // h stores at coherence point (L3)
            if (tid == 0)
                __hip_atomic_store(&flags[blockIdx.x * FPAD], (unsigned int)(t + 1),
                                   __ATOMIC_RELAXED, __HIP_MEMORY_SCOPE_AGENT);
        }
    }
}

// ---------------- final linear: out[b,o] = h[b,:]·w_lin[o,:] + b_lin[o] ----------------
__global__ void k_final(const unsigned short* __restrict__ h, const float* __restrict__ w_lin,
                        const float* __restrict__ b_lin, float* __restrict__ out) {
    const int wave = threadIdx.x >> 6;
    const int lane = threadIdx.x & 63;
    const int o = blockIdx.x * 4 + wave;
    const float4* w4 = (const float4*)(w_lin + (size_t)o * DD);

    float acc[8];
#pragma unroll
    for (int b = 0; b < 8; ++b) acc[b] = 0.f;
#pragma unroll 2
    for (int it = 0; it < 8; ++it) {
        const int k4 = it * 64 + lane;
        float4 wv = w4[k4];
#pragma unroll
        for (int b = 0; b < 8; ++b) {
            ushort4 hv = *(const ushort4*)(h + (size_t)b * DD + 4 * (size_t)k4);
            acc[b] += wv.x * b2f(hv.x) + wv.y * b2f(hv.y) +
                      wv.z * b2f(hv.z) + wv.w * b2f(hv.w);
        }
    }
#pragma unroll
    for (int b = 0; b < 8; ++b) {
        float v = acc[b];
        v += __shfl_xor(v, 32, 64);
        v += __shfl_xor(v, 16, 64);
        v += __shfl_xor(v, 8, 64);
        v += __shfl_xor(v, 4, 64);
        v += __shfl_xor(v, 2, 64);
        v += __shfl_xor(v, 1, 64);
        acc[b] = v;
    }
    if (lane < 8) out[(size_t)lane * NN + o] = acc[lane] + b_lin[o];
}

// ---------------- launch ----------------

extern "C" void kernel_launch(void* const* d_in, const int* in_sizes, int n_in,
                              void* d_out, int out_size, void* d_ws, size_t ws_size,
                              hipStream_t stream) {
    const float* xseq  = (const float*)d_in[0];
    const float* gat_w = (const float*)d_in[1];
    const float* a_src = (const float*)d_in[2];
    const float* a_dst = (const float*)d_in[3];
    const float* g_b   = (const float*)d_in[4];
    const float* w_ih  = (const float*)d_in[5];
    const float* w_hh  = (const float*)d_in[6];
    const float* b_ih  = (const float*)d_in[7];
    const float* b_hh  = (const float*)d_in[8];
    const float* w_lin = (const float*)d_in[9];
    const float* b_lin = (const float*)d_in[10];
    const int*   eidx  = (const int*)d_in[11];
    float* out = (float*)d_out;

    // workspace layout
    unsigned short* seq = (unsigned short*)d_ws;                 // T*B*D bf16 (4 MB)
    unsigned short* WP  = seq + (size_t)TT * BB * DD;            // 64 MB packed weights
    unsigned short* hb0 = WP + (size_t)8192 * KTOT;              // B*D bf16
    unsigned short* hb1 = hb0 + BB * DD;                         // B*D bf16
    unsigned int* flags = (unsigned int*)(hb1 + BB * DD);        // 256*FPAD dwords

    // weight pack (bf16, B-frag swizzled)
    k_pack_w<<<16384, 256, 0, stream>>>(w_ih, w_hh, WP);

    // fused GAT -> seq (bf16)
    k_gat<<<TT, NN, 0, stream>>>(xseq, gat_w, a_src, a_dst, g_b, eidx, seq);

    // zero h buffers + barrier flags (poisoned with 0xAA each timed call!)
    k_zero<<<64, 256, 0, stream>>>((unsigned int*)hb0, flags);

    // persistent cooperative LSTM with fence-free sc1 barrier
    {
        void* kargs[] = {
            (void*)&seq, (void*)&WP, (void*)&b_ih, (void*)&b_hh,
            (void*)&hb0, (void*)&hb1, (void*)&flags,
        };
        hipLaunchCooperativeKernel((const void*)k_lstm_persist, dim3(256), dim3(1024),
                                   kargs, 0, stream);
    }

    // final h is in hb0 after 128 steps
    k_final<<<NN / 4, 256, 0, stream>>>(hb0, w_lin, b_lin, out);
}